// Round 5
// baseline (129.850 us; speedup 1.0000x reference)
//
#include <hip/hip_runtime.h>

// Problem constants (fixed by the reference file).
#define DIN  4096
#define NG   4096          // NUM_GATES = DOUT/3
#define BS   4096
#define RPB  16            // rows per block -> 256 blocks = 1 per CU, whole grid resident
#define BT   1024          // 16 waves
#define NW   16
#define WFL  832           // floats staged per wave per row: 3x dma16 (768) + 1x dma4 (64)

// Wait until at most N vector-memory ops outstanding; lgkm/exp unconstrained.
// N must be a LITERAL (frontend constant check) — hence macro-expanded iters.
#define WAITVM(N) __builtin_amdgcn_s_waitcnt((N) | 0x0F70)

// Async global->LDS DMA. LDS dest = wave-uniform base + lane*size; global src is
// per-lane (so the &4095 row-wrap is done per lane). size must be a literal.
__device__ __forceinline__ void dma16(const float* g, float* lds) {
    __builtin_amdgcn_global_load_lds(
        (const __attribute__((address_space(1))) void*)g,
        (__attribute__((address_space(3))) void*)lds, 16, 0, 0);
}
__device__ __forceinline__ void dma4(const float* g, float* lds) {
    __builtin_amdgcn_global_load_lds(
        (const __attribute__((address_space(1))) void*)g,
        (__attribute__((address_space(3))) void*)lds, 4, 0, 0);
}

// out[b,g] = w0*x[b,(3g+1)&4095] + w1*x[b,(3g+2)&4095] + w2*x[b,(3g+3)&4095] + w3
// (w0..w3) = softmax(wgts[g,0,0..3]). Reference's signals[:, :, ::3] selects only
// row 0 of M = [1,0,0,0,0] -> out = s[...,0]; v4/v5 and rows 1..2 are dead code.
//
// R12: wave-private staging, ZERO barriers, counted vmcnt (T4).
//  - History: every compiler-scheduled variant (R9/R10/R11) = 44-53 us because
//    waits collapse to vmcnt(0) at consumption (worst: __syncthreads drain).
//    R8 (29 us, best) kept a counted DMA queue alive across consumption — but
//    paid 8x 16-wave barrier rendezvous per block.
//  - Here wave v owns gates [256v, 256v+256): its x-footprint is the contiguous
//    wrapped window x[768v .. 768v+770]. Each wave DMAs its OWN 3.25 KB window
//    and waits only its OWN vmcnt — no __syncthreads in the whole kernel.
//  - Steady-state WAITVM(8): next row's 4 DMAs + this row's 4 stores stay in
//    flight across the wait. In-flight/CU = 16 waves x 3.25 KB ~ 52 KB >> the
//    ~9 KB needed to saturate this CU's HBM share.
//  - Fetch-once by construction: a row is touched only by the 16 waves of ONE
//    CU; window overlap (3x) dedupes in that CU's own XCD L2 (R10's cross-XCD
//    duplication impossible).
//  - LDS reads at dword stride 3 (coprime with 32 banks -> 2-way = free);
//    stores are coalesced 256 B wave stores; LDS 2x16x832x4 = 106.5 KB.
__global__ __launch_bounds__(BT, 4) void fredkin_wavepriv(
    const float* __restrict__ x,
    const float* __restrict__ wgts,
    float* __restrict__ out)
{
    // Two objects (even/odd row) so LLVM's per-object LDS-DMA tracking doesn't
    // conservatively drain the other buffer's outstanding DMAs (R8 lesson).
    __shared__ float E[NW][WFL];
    __shared__ float O[NW][WFL];

    const int tid = threadIdx.x;
    const int v   = tid >> 6;        // wave 0..15
    const int l   = tid & 63;        // lane
    const int row0 = blockIdx.x * RPB;

    // Softmax of wgts[g,0,:] for gates g = 256v + l + 64k. Fully consumed
    // before the first DMA is issued -> vmcnt FIFO is clean for manual counting.
    float4 wq[4];
#pragma unroll
    for (int k = 0; k < 4; ++k) {
        const int g = (v << 8) + l + (k << 6);
        float4 r = *reinterpret_cast<const float4*>(wgts + (size_t)g * 12);
        float m  = fmaxf(fmaxf(r.x, r.y), fmaxf(r.z, r.w));
        float e0 = __expf(r.x - m);
        float e1 = __expf(r.y - m);
        float e2 = __expf(r.z - m);
        float e3 = __expf(r.w - m);
        float inv = 1.0f / (e0 + e1 + e2 + e3);
        wq[k] = make_float4(e0 * inv, e1 * inv, e2 * inv, e3 * inv);
    }

    // Per-lane wrapped source offsets (floats) for the 4 DMA ops of a row.
    // Window of wave v = x[(768v + t) & 4095], t = 0..831, staged linearly.
    const int wb = 3 * (v << 8);                  // 768v
    const int s0 = (wb       + (l << 2)) & (DIN - 1);
    const int s1 = (wb + 256 + (l << 2)) & (DIN - 1);
    const int s2 = (wb + 512 + (l << 2)) & (DIN - 1);
    const int s3 = (wb + 768 +  l      ) & (DIN - 1);
    float* We = &E[v][0];
    float* Wo = &O[v][0];

#define STAGE(DST, R_) {                                              \
        const float* xr = x + (size_t)(row0 + (R_)) * DIN;            \
        dma16(xr + s0, (DST));                                        \
        dma16(xr + s1, (DST) + 256);                                  \
        dma16(xr + s2, (DST) + 512);                                  \
        dma4 (xr + s3, (DST) + 768);                                  \
    }

    asm volatile("" ::: "memory");
    STAGE(We, 0)                                   // prologue: row 0 in flight

    // Gate g = 256v + l + 64k reads staged floats t..t+2, t = 3l + 192k + 1
    // (max index 768 at l=63,k=3 — inside the dma4 tail). Bank-conflict-free.
    const int t1 = 3 * l + 1;

    // One pipeline iteration. NWAIT is a LITERAL: # vmem ops newer than this
    // row's own 4 DMAs at the wait point.
    //   FIFO (steady, r=1..14): [dma(r) 4][stores(r-1) 4, dma(r+1) 4] -> 8
    //   r=0:  [dma(0) 4][dma(1) 4]                                    -> 4
    //   r=15: [dma(15) 4][stores(14) 4]                               -> 4
#define FRED_ITER(R_, NWAIT, CUR, NXT, DO_STAGE)                              \
    {                                                                         \
        if (DO_STAGE) STAGE(NXT, (R_) + 1)                                    \
        asm volatile("" ::: "memory");                                        \
        WAITVM(NWAIT);                                                        \
        asm volatile("" ::: "memory");                                        \
        float* orow = out + (size_t)(row0 + (R_)) * NG + (v << 8) + l;        \
        _Pragma("unroll")                                                     \
        for (int k = 0; k < 4; ++k) {                                         \
            const float* p = (CUR) + t1 + 192 * k;                            \
            float e1 = p[0];                                                  \
            float e2 = p[1];                                                  \
            float e3 = p[2];                                                  \
            float o = fmaf(wq[k].x, e1,                                       \
                      fmaf(wq[k].y, e2,                                       \
                      fmaf(wq[k].z, e3, wq[k].w)));                           \
            __builtin_nontemporal_store(o, orow + (k << 6));                  \
        }                                                                     \
    }
    // WAW safety: STAGE(NXT) at iter r overwrites the buffer read at iter r-1;
    // those ds_reads were lgkm-drained into VGPRs before their FMAs
    // (compiler-enforced), which precede this STAGE in program order.

    FRED_ITER( 0, 4, We, Wo, 1)
    FRED_ITER( 1, 8, Wo, We, 1)
    FRED_ITER( 2, 8, We, Wo, 1)
    FRED_ITER( 3, 8, Wo, We, 1)
    FRED_ITER( 4, 8, We, Wo, 1)
    FRED_ITER( 5, 8, Wo, We, 1)
    FRED_ITER( 6, 8, We, Wo, 1)
    FRED_ITER( 7, 8, Wo, We, 1)
    FRED_ITER( 8, 8, We, Wo, 1)
    FRED_ITER( 9, 8, Wo, We, 1)
    FRED_ITER(10, 8, We, Wo, 1)
    FRED_ITER(11, 8, Wo, We, 1)
    FRED_ITER(12, 8, We, Wo, 1)
    FRED_ITER(13, 8, Wo, We, 1)
    FRED_ITER(14, 8, We, Wo, 1)
    FRED_ITER(15, 4, Wo, We, 0)
#undef FRED_ITER
#undef STAGE
}

extern "C" void kernel_launch(void* const* d_in, const int* in_sizes, int n_in,
                              void* d_out, int out_size, void* d_ws, size_t ws_size,
                              hipStream_t stream) {
    const float* x    = (const float*)d_in[0];   // (BS, DIN) fp32
    const float* wgts = (const float*)d_in[1];   // (NG, 3, 4) fp32
    // d_in[2] (connections) is deterministic: (3g+1+j) % DIN — computed inline.
    float* out = (float*)d_out;                  // (BS, NG) fp32

    fredkin_wavepriv<<<dim3(BS / RPB), dim3(BT), 0, stream>>>(x, wgts, out);
}

// Round 6
// 115.719 us; speedup vs baseline: 1.1221x; 1.1221x over previous
//
#include <hip/hip_runtime.h>

// Problem constants (fixed by the reference file).
#define DIN  4096
#define NG   4096          // NUM_GATES = DOUT/3
#define BS   4096
#define RPB  8             // rows per block -> 512 blocks = 2 blocks/CU resident
#define BT   1024          // 16 waves; block covers ALL 4096 gates (4 per thread)

// Wait until at most N (<=15) vector-memory ops outstanding; lgkm/exp free.
#define WAITVM(N) __builtin_amdgcn_s_waitcnt((N) | 0x0F70)

// Async global->LDS DMA, 16B per lane. LDS dest = wave-uniform base + lane*16.
__device__ __forceinline__ void dma16(const float* g, float* lds) {
    __builtin_amdgcn_global_load_lds(
        (const __attribute__((address_space(1))) void*)g,
        (__attribute__((address_space(3))) void*)lds, 16, 0, 0);
}

// out[b,g] = w0*x[b,(3g+1)&4095] + w1*x[b,(3g+2)&4095] + w2*x[b,(3g+3)&4095] + w3
// (w0..w3) = softmax(wgts[g,0,0..3]). Reference's signals[:, :, ::3] selects only
// row 0 of M = [1,0,0,0,0] -> out = s[...,0]; v4/v5 and rows 1..2 are dead code.
//
// R13 = R8's proven skeleton (best: ~29 us) + conflict-free LDS reads.
//  - R8: 4 SEPARATE row buffers (per-object LDS-DMA tracking -> no compiler
//    drain; R12's 2-object/distance-1 variant serialized at 42 us), depth-3
//    prefetch, per-row [WAITVM(counted); s_barrier; DMA(r+3); reads; stores].
//  - New: gate map g = tid + 1024k. LDS reads become dword-stride-3 scalars:
//    bank = (3t+j) mod 32, gcd(3,32)=1 -> exact 2-way aliasing = FREE (m136),
//    vs R8's b128 reads at 48B lane-stride (bank 12t mod 32, period 8 -> ~8-way
//    conflict ~ 2.9x). Stores stay coalesced (4 x 256B wave stores). Row wrap
//    handled by &4095 on 12 precomputed row-invariant indices (no divergent
//    seam read, no shuffle).
//  - vmcnt FIFO per wave per iter: 1 dma16 + 4 stores = 5 ops. NWAIT = #ops
//    newer than this row's own dma at the wait point (exact count, never 0):
//    pro: d0 d1 d2
//    it0: W(2)  bar d3 st0 | it1: W(6)  bar d4 st1 | it2: W(10) bar d5 st2
//    it3: W(14) bar d6 st3 | it4: W(14) bar d7 st4 | it5: W(14) bar st5
//    it6: W(13) bar st6    | it7: W(12) bar st7
//  - WAW safety: DMA(r+3) targets the buffer read at iter r-1; it is issued
//    after barrier(r), and every wave's iter r-1 ds_reads were consumed (lgkm
//    drained into VGPRs before the FMAs/stores) before that wave reached
//    barrier(r) in program order => no race.
//  - LDS 4 x 16 KiB = 64 KiB -> 2 blocks/CU (32 waves/CU); launch_bounds
//    (1024, 8) caps VGPR at 64 so registers don't break 2-block residency.
__global__ __launch_bounds__(BT, 8) void fredkin_ring4(
    const float* __restrict__ x,
    const float* __restrict__ wgts,
    float* __restrict__ out)
{
    // 4 SEPARATE objects so LLVM's per-object LDS-DMA tracking doesn't
    // conservatively drain all outstanding DMAs before each ds_read (R8 lesson,
    // re-confirmed negatively by R12).
    __shared__ float B0[DIN], B1[DIN], B2[DIN], B3[DIN];

    const int tid = threadIdx.x;
    const int w   = tid >> 6;        // wave 0..15
    const int l   = tid & 63;        // lane

    // Softmax of wgts[g,0,:] for gates g = tid + 1024k (row-0 at float offset
    // 12g, 16B aligned). Fully consumed before the first DMA is issued, so the
    // vmcnt FIFO below is exact.
    float4 wq[4];
#pragma unroll
    for (int k = 0; k < 4; ++k) {
        const int g = tid + (k << 10);
        float4 r = *reinterpret_cast<const float4*>(wgts + (size_t)g * 12);
        float m  = fmaxf(fmaxf(r.x, r.y), fmaxf(r.z, r.w));
        float e0 = __expf(r.x - m);
        float e1 = __expf(r.y - m);
        float e2 = __expf(r.z - m);
        float e3 = __expf(r.w - m);
        float inv = 1.0f / (e0 + e1 + e2 + e3);
        wq[k] = make_float4(e0 * inv, e1 * inv, e2 * inv, e3 * inv);
    }

    const int brow = blockIdx.x * RPB;
    const float* xb   = x   + (size_t)brow * DIN;    // block's row 0
    float*       obase = out + (size_t)brow * NG + tid;
    const int doff = (w << 8) + (l << 2);            // wave w stages floats [256w,256w+256)

    // Row-invariant LDS read indices for gate g = tid + 1024k:
    // idx(k,j) = (3g + j) & 4095, j = 1..3. Bank = idx mod 32: conflict-free.
    int idx[4][3];
#pragma unroll
    for (int k = 0; k < 4; ++k) {
        const int jb = 3 * tid + 3072 * k;
#pragma unroll
        for (int j = 0; j < 3; ++j) idx[k][j] = (jb + 1 + j) & (DIN - 1);
    }

#define STAGE(BUF, R_) dma16(xb + (size_t)(R_) * DIN + doff, (BUF) + (w << 8));

    asm volatile("" ::: "memory");
    STAGE(B0, 0)                     // prologue: rows 0..2 in flight
    STAGE(B1, 1)
    STAGE(B2, 2)

#define FRED_ITER(R_, NWAIT, RBUF, WBUF, DO_STAGE)                            \
    {                                                                         \
        asm volatile("" ::: "memory");                                        \
        WAITVM(NWAIT);              /* own dma(R_) retired */                 \
        __builtin_amdgcn_s_barrier(); /* => ALL waves' dma(R_) retired */     \
        asm volatile("" ::: "memory");                                        \
        if (DO_STAGE) STAGE(WBUF, (R_) + 3)                                   \
        float* orow = obase + (size_t)(R_) * NG;                              \
        float o0 = fmaf(wq[0].x, RBUF[idx[0][0]],                             \
                   fmaf(wq[0].y, RBUF[idx[0][1]],                             \
                   fmaf(wq[0].z, RBUF[idx[0][2]], wq[0].w)));                 \
        float o1 = fmaf(wq[1].x, RBUF[idx[1][0]],                             \
                   fmaf(wq[1].y, RBUF[idx[1][1]],                             \
                   fmaf(wq[1].z, RBUF[idx[1][2]], wq[1].w)));                 \
        float o2 = fmaf(wq[2].x, RBUF[idx[2][0]],                             \
                   fmaf(wq[2].y, RBUF[idx[2][1]],                             \
                   fmaf(wq[2].z, RBUF[idx[2][2]], wq[2].w)));                 \
        float o3 = fmaf(wq[3].x, RBUF[idx[3][0]],                             \
                   fmaf(wq[3].y, RBUF[idx[3][1]],                             \
                   fmaf(wq[3].z, RBUF[idx[3][2]], wq[3].w)));                 \
        __builtin_nontemporal_store(o0, orow);                                \
        __builtin_nontemporal_store(o1, orow + 1024);                         \
        __builtin_nontemporal_store(o2, orow + 2048);                         \
        __builtin_nontemporal_store(o3, orow + 3072);                         \
    }

    FRED_ITER(0,  2, B0, B3, 1)
    FRED_ITER(1,  6, B1, B0, 1)
    FRED_ITER(2, 10, B2, B1, 1)
    FRED_ITER(3, 14, B3, B2, 1)
    FRED_ITER(4, 14, B0, B3, 1)
    FRED_ITER(5, 14, B1, B0, 0)
    FRED_ITER(6, 13, B2, B1, 0)
    FRED_ITER(7, 12, B3, B2, 0)
#undef FRED_ITER
#undef STAGE
}

extern "C" void kernel_launch(void* const* d_in, const int* in_sizes, int n_in,
                              void* d_out, int out_size, void* d_ws, size_t ws_size,
                              hipStream_t stream) {
    const float* x    = (const float*)d_in[0];   // (BS, DIN) fp32
    const float* wgts = (const float*)d_in[1];   // (NG, 3, 4) fp32
    // d_in[2] (connections) is deterministic: (3g+1+j) % DIN — computed inline.
    float* out = (float*)d_out;                  // (BS, NG) fp32

    fredkin_ring4<<<dim3(BS / RPB), dim3(BT), 0, stream>>>(x, wgts, out);
}